// Round 1
// baseline (1085.181 us; speedup 1.0000x reference)
//
#include <hip/hip_runtime.h>

// ---------------- problem constants ----------------
#define T_LEN 32768
#define HIDC  128
#define LC    128
#define HOP   256
#define CONDC 512
#define NLAY  4
#define MROWS 49152   // HID*HID*KER rows per layer in kernel predictor

typedef __attribute__((ext_vector_type(8))) short short8;
typedef __attribute__((ext_vector_type(4))) float f32x4;

static __device__ __forceinline__ unsigned short f2b(float f) {
  union { float f; unsigned u; } v; v.f = f;
  unsigned r = v.u + 0x7FFFu + ((v.u >> 16) & 1u);   // RNE
  return (unsigned short)(r >> 16);
}
static __device__ __forceinline__ float b2f(unsigned short h) {
  union { unsigned u; float f; } v; v.u = ((unsigned)h) << 16;
  return v.f;
}

// ---------------- tiny prep kernels ----------------

// cbT[n=b*128+l][ch] = bf16(c[b][ch][l])   (512 x 512)
__global__ void k_cbt(const float* __restrict__ c, unsigned short* __restrict__ cbt) {
  int idx = blockIdx.x * 256 + threadIdx.x;          // 262144
  int n = idx >> 9, ch = idx & 511;
  int b = n >> 7, l = n & 127;
  cbt[idx] = f2b(c[(size_t)(b * CONDC + ch) * LC + l]);
}

// bwT[layer][k][i][o] = bf16(block_w[layer][o][i][k])
__global__ void k_bwt(const float* __restrict__ bw, unsigned short* __restrict__ bwt) {
  int idx = blockIdx.x * 256 + threadIdx.x;          // 196608
  int o = idx & 127, i = (idx >> 7) & 127, kk = idx >> 14;
  int k = kk % 3, layer = kk / 3;
  bwt[idx] = f2b(bw[(size_t)((layer * HIDC + o) * HIDC + i) * 3 + k]);
}

// b_all[(b*4+layer)*128+o][l] = biasp_w[m] . c[b][:][l] + biasp_b[m],  m=layer*128+o
__global__ void k_bias(const float* __restrict__ c, const float* __restrict__ bw,
                       const float* __restrict__ bb, float* __restrict__ ball) {
  int m = blockIdx.x, b = blockIdx.y, l = threadIdx.x;
  const float* crow = c + (size_t)b * CONDC * LC + l;
  const float* wrow = bw + (size_t)m * CONDC;
  float acc = 0.f;
  for (int ch = 0; ch < CONDC; ++ch) acc = fmaf(wrow[ch], crow[(size_t)ch * LC], acc);
  int layer = m >> 7, o = m & 127;
  ball[((size_t)(b * NLAY + layer) * HIDC + o) * LC + l] = acc + bb[m];
}

// h0[b][t][o] = bf16(leaky(pre_w[o]*x[b,t]+pre_b[o], 0.2))
__global__ void k_pre(const float* __restrict__ x, const float* __restrict__ pw,
                      const float* __restrict__ pb, unsigned short* __restrict__ h) {
  int idx = blockIdx.x * 256 + threadIdx.x;          // B*T*32
  int o4 = (idx & 31) << 2;
  int bt = idx >> 5;
  float xv = x[bt];
  float4 w = *(const float4*)(pw + o4);
  float4 bi = *(const float4*)(pb + o4);
  float r0 = fmaf(w.x, xv, bi.x); r0 = r0 >= 0.f ? r0 : 0.2f * r0;
  float r1 = fmaf(w.y, xv, bi.y); r1 = r1 >= 0.f ? r1 : 0.2f * r1;
  float r2 = fmaf(w.z, xv, bi.z); r2 = r2 >= 0.f ? r2 : 0.2f * r2;
  float r3 = fmaf(w.w, xv, bi.w); r3 = r3 >= 0.f ? r3 : 0.2f * r3;
  ushort4 s; s.x = f2b(r0); s.y = f2b(r1); s.z = f2b(r2); s.w = f2b(r3);
  *(ushort4*)(h + (size_t)bt * HIDC + o4) = s;
}

// out[bt] = post_w . h[bt][:] + post_b
__global__ void k_post(const unsigned short* __restrict__ h, const float* __restrict__ pw,
                       const float* __restrict__ pb, float* __restrict__ out) {
  int t = blockIdx.x * 256 + threadIdx.x;            // B*T
  const unsigned short* r = h + (size_t)t * HIDC;
  float acc = 0.f;
#pragma unroll
  for (int o = 0; o < HIDC; o += 8) {
    int4 w = *(const int4*)(r + o);
    int ws_[4] = {w.x, w.y, w.z, w.w};
#pragma unroll
    for (int j = 0; j < 4; ++j) {
      unsigned v = (unsigned)ws_[j];
      acc = fmaf(b2f((unsigned short)(v & 0xFFFFu)), pw[o + j * 2], acc);
      acc = fmaf(b2f((unsigned short)(v >> 16)),     pw[o + j * 2 + 1], acc);
    }
  }
  out[t] = acc + pb[0];
}

// ---------------- kernel-predictor GEMM ----------------
// C[n][m] = bf16( A[m][:] . cbT[n][:] + bias[m] ),  M=49152 (one layer), N=512, K=512
__global__ __launch_bounds__(256) void k_kpred(
    const float* __restrict__ A, const float* __restrict__ bias,
    const unsigned short* __restrict__ Bt, unsigned short* __restrict__ C) {
  __shared__ __align__(16) unsigned short As[128 * 72];
  __shared__ __align__(16) unsigned short Bs[128 * 72];
  const int mtile = blockIdx.x * 128;
  const int ntile = blockIdx.y * 128;
  const int tid = threadIdx.x;
  const int wave = tid >> 6, lane = tid & 63;
  const int wm = (wave & 1) * 64, wn = (wave >> 1) * 64;
  const int lm = lane & 15, quad = lane >> 4;
  f32x4 acc[4][4] = {};
  for (int k0 = 0; k0 < CONDC; k0 += 64) {
#pragma unroll
    for (int it = 0; it < 8; ++it) {                  // A: 128x64 fp32 -> bf16 LDS
      int idx = it * 256 + tid;
      int row = idx >> 4, kq = (idx & 15) << 2;
      float4 v = *(const float4*)(A + (size_t)(mtile + row) * CONDC + k0 + kq);
      ushort4 s; s.x = f2b(v.x); s.y = f2b(v.y); s.z = f2b(v.z); s.w = f2b(v.w);
      *(ushort4*)(&As[row * 72 + kq]) = s;
    }
#pragma unroll
    for (int it = 0; it < 4; ++it) {                  // B: 128x64 bf16 LDS
      int idx = it * 256 + tid;
      int row = idx >> 3, k8 = (idx & 7) << 3;
      *(int4*)(&Bs[row * 72 + k8]) = *(const int4*)(Bt + (size_t)(ntile + row) * CONDC + k0 + k8);
    }
    __syncthreads();
#pragma unroll
    for (int kk = 0; kk < 2; ++kk) {
      short8 af[4], bf[4];
#pragma unroll
      for (int mb = 0; mb < 4; ++mb)
        af[mb] = *(const short8*)(&As[(wm + mb * 16 + lm) * 72 + kk * 32 + quad * 8]);
#pragma unroll
      for (int nb = 0; nb < 4; ++nb)
        bf[nb] = *(const short8*)(&Bs[(wn + nb * 16 + lm) * 72 + kk * 32 + quad * 8]);
#pragma unroll
      for (int mb = 0; mb < 4; ++mb)
#pragma unroll
        for (int nb = 0; nb < 4; ++nb)
          acc[mb][nb] = __builtin_amdgcn_mfma_f32_16x16x32_bf16(af[mb], bf[nb], acc[mb][nb], 0, 0, 0);
    }
    __syncthreads();
  }
#pragma unroll
  for (int mb = 0; mb < 4; ++mb) {
    int m0 = mtile + wm + mb * 16 + quad * 4;
    float b0 = bias[m0], b1 = bias[m0 + 1], b2 = bias[m0 + 2], b3 = bias[m0 + 3];
#pragma unroll
    for (int nb = 0; nb < 4; ++nb) {
      int n = ntile + wn + nb * 16 + lm;
      f32x4 v = acc[mb][nb];
      ushort4 s;
      s.x = f2b(v.x + b0); s.y = f2b(v.y + b1); s.z = f2b(v.z + b2); s.w = f2b(v.w + b3);
      *(ushort4*)(&C[(size_t)n * MROWS + m0]) = s;
    }
  }
}

// ---------------- LVC (location-variable conv) + leaky(3) ----------------
// per (b,l): out[o][s] = sum_{i,k} h[b][l*256+s+k-1][i] * K[(i*128+o)*3+k] + bias, leaky 3
__global__ __launch_bounds__(512) void k_lvc(
    const unsigned short* __restrict__ hin, const unsigned short* __restrict__ kbuf,
    const float* __restrict__ ball, unsigned short* __restrict__ hout, int layer) {
  __shared__ __align__(16) unsigned short Hs[258 * 40];
  __shared__ __align__(16) unsigned short As[3 * 128 * 40];
  const int l = blockIdx.x, b = blockIdx.y;
  const int t0 = l * HOP;
  const int tid = threadIdx.x;
  const int wave = tid >> 6, lane = tid & 63;
  const int wm = (wave & 1) * 64, wn = (wave >> 1) * 64;
  const int lm = lane & 15, quad = lane >> 4;
  const unsigned short* hb = hin + (size_t)b * T_LEN * HIDC;
  const unsigned short* kb = kbuf + (size_t)(b * LC + l) * MROWS;
  f32x4 acc[4][4] = {};
  for (int ic = 0; ic < HIDC; ic += 32) {
    __syncthreads();
#pragma unroll
    for (int p = 0; p < 5; ++p) {                     // H: 258 x 32 bf16
      int idx = p * 512 + tid;
      if (idx < 258 * 8) {
        int u = idx >> 3, i4 = (idx & 7) << 2;
        int t = t0 + u - 1;
        ushort4 v; v.x = v.y = v.z = v.w = 0;
        if (t >= 0 && t < T_LEN) v = *(const ushort4*)(hb + (size_t)t * HIDC + ic + i4);
        *(ushort4*)(&Hs[u * 40 + i4]) = v;
      }
    }
#pragma unroll
    for (int p = 0; p < 24; ++p) {                    // A: 3 taps x 128 o x 32 i
      int idx = p * 512 + tid;
      int o = idx & 127, ii = (idx >> 7) & 31, k = idx >> 12;
      As[(k * 128 + o) * 40 + ii] = kb[((size_t)(ic + ii) * HIDC + o) * 3 + k];
    }
    __syncthreads();
#pragma unroll
    for (int k = 0; k < 3; ++k) {
      short8 af[4], bf[4];
#pragma unroll
      for (int mb = 0; mb < 4; ++mb)
        af[mb] = *(const short8*)(&As[(k * 128 + wm + mb * 16 + lm) * 40 + quad * 8]);
#pragma unroll
      for (int nb = 0; nb < 4; ++nb)
        bf[nb] = *(const short8*)(&Hs[(wn + nb * 16 + lm + k) * 40 + quad * 8]);
#pragma unroll
      for (int mb = 0; mb < 4; ++mb)
#pragma unroll
        for (int nb = 0; nb < 4; ++nb)
          acc[mb][nb] = __builtin_amdgcn_mfma_f32_16x16x32_bf16(af[mb], bf[nb], acc[mb][nb], 0, 0, 0);
    }
  }
  const float* bp = ball + (size_t)(b * NLAY + layer) * HIDC * LC + l;
#pragma unroll
  for (int mb = 0; mb < 4; ++mb) {
    int o0 = wm + mb * 16 + quad * 4;
    float bi[4];
#pragma unroll
    for (int j = 0; j < 4; ++j) bi[j] = bp[(size_t)(o0 + j) * LC];
#pragma unroll
    for (int nb = 0; nb < 4; ++nb) {
      int s = wn + nb * 16 + lm;
      f32x4 v = acc[mb][nb];
      float r0 = v.x + bi[0]; r0 = r0 >= 0.f ? r0 : 3.f * r0;
      float r1 = v.y + bi[1]; r1 = r1 >= 0.f ? r1 : 3.f * r1;
      float r2 = v.z + bi[2]; r2 = r2 >= 0.f ? r2 : 3.f * r2;
      float r3 = v.w + bi[3]; r3 = r3 >= 0.f ? r3 : 3.f * r3;
      ushort4 st; st.x = f2b(r0); st.y = f2b(r1); st.z = f2b(r2); st.w = f2b(r3);
      *(ushort4*)(&hout[((size_t)b * T_LEN + t0 + s) * HIDC + o0]) = st;
    }
  }
}

// ---------------- dilated conv + leaky(3) ----------------
__global__ __launch_bounds__(512) void k_dconv(
    const unsigned short* __restrict__ hin, const unsigned short* __restrict__ bwt,
    const float* __restrict__ bb, unsigned short* __restrict__ hout, int d) {
  __shared__ __align__(16) unsigned short Hs[310 * 40];
  __shared__ __align__(16) unsigned short As[3 * 128 * 40];
  const int tb = blockIdx.x * HOP, b = blockIdx.y;
  const int U8 = (HOP + 2 * d) * 8;
  const int tid = threadIdx.x;
  const int wave = tid >> 6, lane = tid & 63;
  const int wm = (wave & 1) * 64, wn = (wave >> 1) * 64;
  const int lm = lane & 15, quad = lane >> 4;
  const unsigned short* hb = hin + (size_t)b * T_LEN * HIDC;
  f32x4 acc[4][4] = {};
  for (int ic = 0; ic < HIDC; ic += 32) {
    __syncthreads();
#pragma unroll
    for (int p = 0; p < 5; ++p) {
      int idx = p * 512 + tid;
      if (idx < U8) {
        int u = idx >> 3, i4 = (idx & 7) << 2;
        int t = tb + u - d;
        ushort4 v; v.x = v.y = v.z = v.w = 0;
        if (t >= 0 && t < T_LEN) v = *(const ushort4*)(hb + (size_t)t * HIDC + ic + i4);
        *(ushort4*)(&Hs[u * 40 + i4]) = v;
      }
    }
#pragma unroll
    for (int p = 0; p < 24; ++p) {
      int idx = p * 512 + tid;
      int o = idx & 127, ii = (idx >> 7) & 31, k = idx >> 12;
      As[(k * 128 + o) * 40 + ii] = bwt[(size_t)(k * HIDC + ic + ii) * HIDC + o];
    }
    __syncthreads();
#pragma unroll
    for (int k = 0; k < 3; ++k) {
      short8 af[4], bf[4];
#pragma unroll
      for (int mb = 0; mb < 4; ++mb)
        af[mb] = *(const short8*)(&As[(k * 128 + wm + mb * 16 + lm) * 40 + quad * 8]);
#pragma unroll
      for (int nb = 0; nb < 4; ++nb)
        bf[nb] = *(const short8*)(&Hs[(wn + nb * 16 + lm + k * d) * 40 + quad * 8]);
#pragma unroll
      for (int mb = 0; mb < 4; ++mb)
#pragma unroll
        for (int nb = 0; nb < 4; ++nb)
          acc[mb][nb] = __builtin_amdgcn_mfma_f32_16x16x32_bf16(af[mb], bf[nb], acc[mb][nb], 0, 0, 0);
    }
  }
#pragma unroll
  for (int mb = 0; mb < 4; ++mb) {
    int o0 = wm + mb * 16 + quad * 4;
    float bi[4];
#pragma unroll
    for (int j = 0; j < 4; ++j) bi[j] = bb[o0 + j];
#pragma unroll
    for (int nb = 0; nb < 4; ++nb) {
      int s = wn + nb * 16 + lm;
      f32x4 v = acc[mb][nb];
      float r0 = v.x + bi[0]; r0 = r0 >= 0.f ? r0 : 3.f * r0;
      float r1 = v.y + bi[1]; r1 = r1 >= 0.f ? r1 : 3.f * r1;
      float r2 = v.z + bi[2]; r2 = r2 >= 0.f ? r2 : 3.f * r2;
      float r3 = v.w + bi[3]; r3 = r3 >= 0.f ? r3 : 3.f * r3;
      ushort4 st; st.x = f2b(r0); st.y = f2b(r1); st.z = f2b(r2); st.w = f2b(r3);
      *(ushort4*)(&hout[((size_t)b * T_LEN + tb + s) * HIDC + o0]) = st;
    }
  }
}

// ---------------- launch ----------------
extern "C" void kernel_launch(void* const* d_in, const int* in_sizes, int n_in,
                              void* d_out, int out_size, void* d_ws, size_t ws_size,
                              hipStream_t stream) {
  const float* x        = (const float*)d_in[0];
  const float* c        = (const float*)d_in[1];
  const float* kernel_w = (const float*)d_in[2];
  const float* kernel_b = (const float*)d_in[3];
  const float* biasp_w  = (const float*)d_in[4];
  const float* biasp_b  = (const float*)d_in[5];
  const float* pre_w    = (const float*)d_in[6];
  const float* pre_b    = (const float*)d_in[7];
  const float* block_w  = (const float*)d_in[8];
  const float* block_b  = (const float*)d_in[9];
  const float* post_w   = (const float*)d_in[10];
  const float* post_b   = (const float*)d_in[11];
  float* out = (float*)d_out;

  char* ws = (char*)d_ws;
  unsigned short* h0   = (unsigned short*)ws;                    // 33,554,432 B
  unsigned short* h1   = (unsigned short*)(ws + 33554432);       // 33,554,432 B
  unsigned short* kbuf = (unsigned short*)(ws + 67108864);       // 50,331,648 B
  float*          ball = (float*)(ws + 117440512);               //  1,048,576 B
  unsigned short* cbt  = (unsigned short*)(ws + 118489088);      //    524,288 B
  unsigned short* bwt  = (unsigned short*)(ws + 119013376);      //    393,216 B
  // total 119,406,592 B

  k_cbt<<<1024, 256, 0, stream>>>(c, cbt);
  k_bwt<<<768, 256, 0, stream>>>(block_w, bwt);
  k_bias<<<dim3(512, 4), 128, 0, stream>>>(c, biasp_w, biasp_b, ball);
  k_pre<<<16384, 256, 0, stream>>>(x, pre_w, pre_b, h0);

  unsigned short* cur = h0;
  unsigned short* nxt = h1;
  const int dils[4] = {1, 3, 9, 27};
  for (int layer = 0; layer < 4; ++layer) {
    k_kpred<<<dim3(384, 4), 256, 0, stream>>>(kernel_w + (size_t)layer * MROWS * CONDC,
                                              kernel_b + (size_t)layer * MROWS, cbt, kbuf);
    k_lvc<<<dim3(128, 4), 512, 0, stream>>>(cur, kbuf, ball, nxt, layer);
    unsigned short* t = cur; cur = nxt; nxt = t;
    k_dconv<<<dim3(128, 4), 512, 0, stream>>>(cur, bwt + (size_t)layer * 3 * HIDC * HIDC,
                                              block_b + layer * HIDC, nxt, dils[layer]);
    t = cur; cur = nxt; nxt = t;
  }
  k_post<<<512, 256, 0, stream>>>(cur, post_w, post_b, out);
}

// Round 3
// 1050.752 us; speedup vs baseline: 1.0328x; 1.0328x over previous
//
#include <hip/hip_runtime.h>

// ---------------- problem constants ----------------
#define T_LEN 32768
#define HIDC  128
#define LC    128
#define HOP   256
#define CONDC 512
#define NLAY  4
#define MROWS 49152   // HID*HID*KER rows per layer in kernel predictor

typedef __attribute__((ext_vector_type(8))) short short8;
typedef __attribute__((ext_vector_type(4))) float f32x4;

static __device__ __forceinline__ unsigned short f2b(float f) {
  union { float f; unsigned u; } v; v.f = f;
  unsigned r = v.u + 0x7FFFu + ((v.u >> 16) & 1u);   // RNE
  return (unsigned short)(r >> 16);
}
static __device__ __forceinline__ float b2f(unsigned short h) {
  union { unsigned u; float f; } v; v.u = ((unsigned)h) << 16;
  return v.f;
}

// ---------------- tiny prep kernels ----------------

// cbT[n=b*128+l][ch] = bf16(c[b][ch][l])   (512 x 512)
__global__ void k_cbt(const float* __restrict__ c, unsigned short* __restrict__ cbt) {
  int idx = blockIdx.x * 256 + threadIdx.x;          // 262144
  int n = idx >> 9, ch = idx & 511;
  int b = n >> 7, l = n & 127;
  cbt[idx] = f2b(c[(size_t)(b * CONDC + ch) * LC + l]);
}

// bwT[layer][k][o][i] = bf16(block_w[layer][o][i][k])   (vec-load friendly for dconv)
__global__ void k_bwt(const float* __restrict__ bw, unsigned short* __restrict__ bwt) {
  int idx = blockIdx.x * 256 + threadIdx.x;          // 196608
  int i = idx & 127, o = (idx >> 7) & 127, kl = idx >> 14;  // kl = layer*3+k
  int k = kl % 3, layer = kl / 3;
  bwt[idx] = f2b(bw[((size_t)(layer * HIDC + o) * HIDC + i) * 3 + k]);
}

// b_all[(b*4+layer)*128+o][l] = biasp_w[m] . c[b][:][l] + biasp_b[m],  m=layer*128+o
__global__ void k_bias(const float* __restrict__ c, const float* __restrict__ bw,
                       const float* __restrict__ bb, float* __restrict__ ball) {
  int m = blockIdx.x, b = blockIdx.y, l = threadIdx.x;
  const float* crow = c + (size_t)b * CONDC * LC + l;
  const float* wrow = bw + (size_t)m * CONDC;
  float acc = 0.f;
  for (int ch = 0; ch < CONDC; ++ch) acc = fmaf(wrow[ch], crow[(size_t)ch * LC], acc);
  int layer = m >> 7, o = m & 127;
  ball[((size_t)(b * NLAY + layer) * HIDC + o) * LC + l] = acc + bb[m];
}

// h0[b][t][o] = bf16(leaky(pre_w[o]*x[b,t]+pre_b[o], 0.2))
__global__ void k_pre(const float* __restrict__ x, const float* __restrict__ pw,
                      const float* __restrict__ pb, unsigned short* __restrict__ h) {
  int idx = blockIdx.x * 256 + threadIdx.x;          // B*T*32
  int o4 = (idx & 31) << 2;
  int bt = idx >> 5;
  float xv = x[bt];
  float4 w = *(const float4*)(pw + o4);
  float4 bi = *(const float4*)(pb + o4);
  float r0 = fmaf(w.x, xv, bi.x); r0 = r0 >= 0.f ? r0 : 0.2f * r0;
  float r1 = fmaf(w.y, xv, bi.y); r1 = r1 >= 0.f ? r1 : 0.2f * r1;
  float r2 = fmaf(w.z, xv, bi.z); r2 = r2 >= 0.f ? r2 : 0.2f * r2;
  float r3 = fmaf(w.w, xv, bi.w); r3 = r3 >= 0.f ? r3 : 0.2f * r3;
  ushort4 s; s.x = f2b(r0); s.y = f2b(r1); s.z = f2b(r2); s.w = f2b(r3);
  *(ushort4*)(h + (size_t)bt * HIDC + o4) = s;
}

// out[bt] = post_w . h[bt][:] + post_b
__global__ void k_post(const unsigned short* __restrict__ h, const float* __restrict__ pw,
                       const float* __restrict__ pb, float* __restrict__ out) {
  int t = blockIdx.x * 256 + threadIdx.x;            // B*T
  const unsigned short* r = h + (size_t)t * HIDC;
  float acc = 0.f;
#pragma unroll
  for (int o = 0; o < HIDC; o += 8) {
    int4 w = *(const int4*)(r + o);
    int ws_[4] = {w.x, w.y, w.z, w.w};
#pragma unroll
    for (int j = 0; j < 4; ++j) {
      unsigned v = (unsigned)ws_[j];
      acc = fmaf(b2f((unsigned short)(v & 0xFFFFu)), pw[o + j * 2], acc);
      acc = fmaf(b2f((unsigned short)(v >> 16)),     pw[o + j * 2 + 1], acc);
    }
  }
  out[t] = acc + pb[0];
}

// ---------------- kernel-predictor GEMM (m-permuted output) ----------------
// Output C[n][m'] with m' = k*16384 + o*128 + i  (kbuf layout [n][k][o][i]).
// A-row for tile row r is kernel_w row  r*384 + o*3 + k  (k,o block-constant).
__global__ __launch_bounds__(256) void k_kpred(
    const float* __restrict__ A, const float* __restrict__ bias,
    const unsigned short* __restrict__ Bt, unsigned short* __restrict__ C) {
  __shared__ __align__(16) unsigned short As[128 * 72];
  __shared__ __align__(16) unsigned short Bs[128 * 72];
  const int mtile = blockIdx.x * 128;
  const int oc = (blockIdx.x & 127) * 3 + (blockIdx.x >> 7);  // o*3 + k
  const int ntile = blockIdx.y * 128;
  const int tid = threadIdx.x;
  const int wave = tid >> 6, lane = tid & 63;
  const int wm = (wave & 1) * 64, wn = (wave >> 1) * 64;
  const int lm = lane & 15, quad = lane >> 4;
  f32x4 acc[4][4] = {};
  for (int k0 = 0; k0 < CONDC; k0 += 64) {
#pragma unroll
    for (int it = 0; it < 8; ++it) {                  // A: 128x64 fp32 -> bf16 LDS (row-permuted)
      int idx = it * 256 + tid;
      int row = idx >> 4, kq = (idx & 15) << 2;
      float4 v = *(const float4*)(A + ((size_t)row * 384 + oc) * CONDC + k0 + kq);
      ushort4 s; s.x = f2b(v.x); s.y = f2b(v.y); s.z = f2b(v.z); s.w = f2b(v.w);
      *(ushort4*)(&As[row * 72 + kq]) = s;
    }
#pragma unroll
    for (int it = 0; it < 4; ++it) {                  // B: 128x64 bf16 LDS
      int idx = it * 256 + tid;
      int row = idx >> 3, k8 = (idx & 7) << 3;
      *(int4*)(&Bs[row * 72 + k8]) = *(const int4*)(Bt + (size_t)(ntile + row) * CONDC + k0 + k8);
    }
    __syncthreads();
#pragma unroll
    for (int kk = 0; kk < 2; ++kk) {
      short8 af[4], bf[4];
#pragma unroll
      for (int mb = 0; mb < 4; ++mb)
        af[mb] = *(const short8*)(&As[(wm + mb * 16 + lm) * 72 + kk * 32 + quad * 8]);
#pragma unroll
      for (int nb = 0; nb < 4; ++nb)
        bf[nb] = *(const short8*)(&Bs[(wn + nb * 16 + lm) * 72 + kk * 32 + quad * 8]);
#pragma unroll
      for (int mb = 0; mb < 4; ++mb)
#pragma unroll
        for (int nb = 0; nb < 4; ++nb)
          acc[mb][nb] = __builtin_amdgcn_mfma_f32_16x16x32_bf16(af[mb], bf[nb], acc[mb][nb], 0, 0, 0);
    }
    __syncthreads();
  }
#pragma unroll
  for (int mb = 0; mb < 4; ++mb) {
    int i0 = wm + mb * 16 + quad * 4;                 // tile-local i
    int m0 = mtile + i0;                              // global m'
    float b0 = bias[(size_t)i0 * 384 + oc];
    float b1 = bias[(size_t)(i0 + 1) * 384 + oc];
    float b2 = bias[(size_t)(i0 + 2) * 384 + oc];
    float b3 = bias[(size_t)(i0 + 3) * 384 + oc];
#pragma unroll
    for (int nb = 0; nb < 4; ++nb) {
      int n = ntile + wn + nb * 16 + lm;
      f32x4 v = acc[mb][nb];
      ushort4 s;
      s.x = f2b(v.x + b0); s.y = f2b(v.y + b1); s.z = f2b(v.z + b2); s.w = f2b(v.w + b3);
      *(ushort4*)(&C[(size_t)n * MROWS + m0]) = s;
    }
  }
}

// ---------------- LVC (location-variable conv) + leaky(3) ----------------
// kbuf layout [n][k][o][i]; all staging 16 B vectorized.
__global__ __launch_bounds__(512) void k_lvc(
    const unsigned short* __restrict__ hin, const unsigned short* __restrict__ kbuf,
    const float* __restrict__ ball, unsigned short* __restrict__ hout, int layer) {
  __shared__ __align__(16) unsigned short Hs[258 * 40];
  __shared__ __align__(16) unsigned short As[3 * 128 * 40];
  const int l = blockIdx.x, b = blockIdx.y;
  const int t0 = l * HOP;
  const int tid = threadIdx.x;
  const int wave = tid >> 6, lane = tid & 63;
  const int wm = (wave & 1) * 64, wn = (wave >> 1) * 64;
  const int lm = lane & 15, quad = lane >> 4;
  const unsigned short* hb = hin + (size_t)b * T_LEN * HIDC;
  const unsigned short* kb = kbuf + (size_t)(b * LC + l) * MROWS;
  f32x4 acc[4][4] = {};
  for (int ic = 0; ic < HIDC; ic += 32) {
    __syncthreads();
#pragma unroll
    for (int p = 0; p < 3; ++p) {                     // H: 258 rows x 32 ch, int4
      int idx = p * 512 + tid;
      if (idx < 258 * 4) {
        int u = idx >> 2, i8 = (idx & 3) << 3;
        int t = t0 + u - 1;
        int4 v = {0, 0, 0, 0};
        if (t >= 0 && t < T_LEN) v = *(const int4*)(hb + (size_t)t * HIDC + ic + i8);
        *(int4*)(&Hs[u * 40 + i8]) = v;
      }
    }
#pragma unroll
    for (int p = 0; p < 3; ++p) {                     // A: 384 rows x 32 ch, int4
      int idx = p * 512 + tid;
      int ko = idx >> 2, i8 = (idx & 3) << 3;
      *(int4*)(&As[ko * 40 + i8]) = *(const int4*)(kb + (size_t)ko * HIDC + ic + i8);
    }
    __syncthreads();
#pragma unroll
    for (int k = 0; k < 3; ++k) {
      short8 af[4], bf[4];
#pragma unroll
      for (int mb = 0; mb < 4; ++mb)
        af[mb] = *(const short8*)(&As[(k * 128 + wm + mb * 16 + lm) * 40 + quad * 8]);
#pragma unroll
      for (int nb = 0; nb < 4; ++nb)
        bf[nb] = *(const short8*)(&Hs[(wn + nb * 16 + lm + k) * 40 + quad * 8]);
#pragma unroll
      for (int mb = 0; mb < 4; ++mb)
#pragma unroll
        for (int nb = 0; nb < 4; ++nb)
          acc[mb][nb] = __builtin_amdgcn_mfma_f32_16x16x32_bf16(af[mb], bf[nb], acc[mb][nb], 0, 0, 0);
    }
  }
  const float* bp = ball + (size_t)(b * NLAY + layer) * HIDC * LC + l;
#pragma unroll
  for (int mb = 0; mb < 4; ++mb) {
    int o0 = wm + mb * 16 + quad * 4;
    float bi[4];
#pragma unroll
    for (int j = 0; j < 4; ++j) bi[j] = bp[(size_t)(o0 + j) * LC];
#pragma unroll
    for (int nb = 0; nb < 4; ++nb) {
      int s = wn + nb * 16 + lm;
      f32x4 v = acc[mb][nb];
      float r0 = v.x + bi[0]; r0 = r0 >= 0.f ? r0 : 3.f * r0;
      float r1 = v.y + bi[1]; r1 = r1 >= 0.f ? r1 : 3.f * r1;
      float r2 = v.z + bi[2]; r2 = r2 >= 0.f ? r2 : 3.f * r2;
      float r3 = v.w + bi[3]; r3 = r3 >= 0.f ? r3 : 3.f * r3;
      ushort4 st; st.x = f2b(r0); st.y = f2b(r1); st.z = f2b(r2); st.w = f2b(r3);
      *(ushort4*)(&hout[((size_t)b * T_LEN + t0 + s) * HIDC + o0]) = st;
    }
  }
}

// ---------------- dilated conv + leaky(3) ----------------
// bwt layout [k][o][i]; all staging 16 B vectorized.
__global__ __launch_bounds__(512) void k_dconv(
    const unsigned short* __restrict__ hin, const unsigned short* __restrict__ bwt,
    const float* __restrict__ bb, unsigned short* __restrict__ hout, int d) {
  __shared__ __align__(16) unsigned short Hs[310 * 40];
  __shared__ __align__(16) unsigned short As[3 * 128 * 40];
  const int tb = blockIdx.x * HOP, b = blockIdx.y;
  const int U4 = (HOP + 2 * d) * 4;
  const int tid = threadIdx.x;
  const int wave = tid >> 6, lane = tid & 63;
  const int wm = (wave & 1) * 64, wn = (wave >> 1) * 64;
  const int lm = lane & 15, quad = lane >> 4;
  const unsigned short* hb = hin + (size_t)b * T_LEN * HIDC;
  f32x4 acc[4][4] = {};
  for (int ic = 0; ic < HIDC; ic += 32) {
    __syncthreads();
#pragma unroll
    for (int p = 0; p < 3; ++p) {                     // H: (256+2d) rows x 32 ch, int4
      int idx = p * 512 + tid;
      if (idx < U4) {
        int u = idx >> 2, i8 = (idx & 3) << 3;
        int t = tb + u - d;
        int4 v = {0, 0, 0, 0};
        if (t >= 0 && t < T_LEN) v = *(const int4*)(hb + (size_t)t * HIDC + ic + i8);
        *(int4*)(&Hs[u * 40 + i8]) = v;
      }
    }
#pragma unroll
    for (int p = 0; p < 3; ++p) {                     // A: 384 rows x 32 ch, int4
      int idx = p * 512 + tid;
      int ko = idx >> 2, i8 = (idx & 3) << 3;
      *(int4*)(&As[ko * 40 + i8]) = *(const int4*)(bwt + (size_t)ko * HIDC + ic + i8);
    }
    __syncthreads();
#pragma unroll
    for (int k = 0; k < 3; ++k) {
      short8 af[4], bf[4];
#pragma unroll
      for (int mb = 0; mb < 4; ++mb)
        af[mb] = *(const short8*)(&As[(k * 128 + wm + mb * 16 + lm) * 40 + quad * 8]);
#pragma unroll
      for (int nb = 0; nb < 4; ++nb)
        bf[nb] = *(const short8*)(&Hs[(wn + nb * 16 + lm + k * d) * 40 + quad * 8]);
#pragma unroll
      for (int mb = 0; mb < 4; ++mb)
#pragma unroll
        for (int nb = 0; nb < 4; ++nb)
          acc[mb][nb] = __builtin_amdgcn_mfma_f32_16x16x32_bf16(af[mb], bf[nb], acc[mb][nb], 0, 0, 0);
    }
  }
#pragma unroll
  for (int mb = 0; mb < 4; ++mb) {
    int o0 = wm + mb * 16 + quad * 4;
    float bi[4];
#pragma unroll
    for (int j = 0; j < 4; ++j) bi[j] = bb[o0 + j];
#pragma unroll
    for (int nb = 0; nb < 4; ++nb) {
      int s = wn + nb * 16 + lm;
      f32x4 v = acc[mb][nb];
      float r0 = v.x + bi[0]; r0 = r0 >= 0.f ? r0 : 3.f * r0;
      float r1 = v.y + bi[1]; r1 = r1 >= 0.f ? r1 : 3.f * r1;
      float r2 = v.z + bi[2]; r2 = r2 >= 0.f ? r2 : 3.f * r2;
      float r3 = v.w + bi[3]; r3 = r3 >= 0.f ? r3 : 3.f * r3;
      ushort4 st; st.x = f2b(r0); st.y = f2b(r1); st.z = f2b(r2); st.w = f2b(r3);
      *(ushort4*)(&hout[((size_t)b * T_LEN + tb + s) * HIDC + o0]) = st;
    }
  }
}

// ---------------- launch ----------------
extern "C" void kernel_launch(void* const* d_in, const int* in_sizes, int n_in,
                              void* d_out, int out_size, void* d_ws, size_t ws_size,
                              hipStream_t stream) {
  const float* x        = (const float*)d_in[0];
  const float* c        = (const float*)d_in[1];
  const float* kernel_w = (const float*)d_in[2];
  const float* kernel_b = (const float*)d_in[3];
  const float* biasp_w  = (const float*)d_in[4];
  const float* biasp_b  = (const float*)d_in[5];
  const float* pre_w    = (const float*)d_in[6];
  const float* pre_b    = (const float*)d_in[7];
  const float* block_w  = (const float*)d_in[8];
  const float* block_b  = (const float*)d_in[9];
  const float* post_w   = (const float*)d_in[10];
  const float* post_b   = (const float*)d_in[11];
  float* out = (float*)d_out;

  char* ws = (char*)d_ws;
  unsigned short* h0   = (unsigned short*)ws;                    // 33,554,432 B
  unsigned short* h1   = (unsigned short*)(ws + 33554432);       // 33,554,432 B
  unsigned short* kbuf = (unsigned short*)(ws + 67108864);       // 50,331,648 B
  float*          ball = (float*)(ws + 117440512);               //  1,048,576 B
  unsigned short* cbt  = (unsigned short*)(ws + 118489088);      //    524,288 B
  unsigned short* bwt  = (unsigned short*)(ws + 119013376);      //    393,216 B
  // total 119,406,592 B

  k_cbt<<<1024, 256, 0, stream>>>(c, cbt);
  k_bwt<<<768, 256, 0, stream>>>(block_w, bwt);
  k_bias<<<dim3(512, 4), 128, 0, stream>>>(c, biasp_w, biasp_b, ball);
  k_pre<<<16384, 256, 0, stream>>>(x, pre_w, pre_b, h0);

  unsigned short* cur = h0;
  unsigned short* nxt = h1;
  const int dils[4] = {1, 3, 9, 27};
  for (int layer = 0; layer < 4; ++layer) {
    k_kpred<<<dim3(384, 4), 256, 0, stream>>>(kernel_w + (size_t)layer * MROWS * CONDC,
                                              kernel_b + (size_t)layer * MROWS, cbt, kbuf);
    k_lvc<<<dim3(128, 4), 512, 0, stream>>>(cur, kbuf, ball, nxt, layer);
    unsigned short* t = cur; cur = nxt; nxt = t;
    k_dconv<<<dim3(128, 4), 512, 0, stream>>>(cur, bwt + (size_t)layer * 3 * HIDC * HIDC,
                                              block_b + layer * HIDC, nxt, dils[layer]);
    t = cur; cur = nxt; nxt = t;
  }
  k_post<<<512, 256, 0, stream>>>(cur, post_w, post_b, out);
}